// Round 6
// baseline (2223.637 us; speedup 1.0000x reference)
//
#include <hip/hip_runtime.h>

// ---------------------------------------------------------------------------
// AdderNet 6-layer stack on MI355X (gfx950).
// out[n,o,p] = -sum_k |x[p,k] - w[o,k]|   (VALU-bound; no MFMA possible)
//
// R6: LDS-free conv (lane = pixel, weights wave-uniform -> SGPR s_load,
// x chunk in xreg[32] VGPRs reused across OB och). Inner loop = v_sub +
// v_add(|mod|) per MAC. No LDS, no barriers, no split-K.
// Fixes vs R5: __launch_bounds__(128,4) pins VGPR cap at 128 (R3/R5 both
// register-starved at 44 VGPR -> load re-materialization, 732MB FETCH);
// 2-wave blocks + och-group counts sized for per-CU load balance.
// ---------------------------------------------------------------------------

template <int OB, bool IS3x3>
__global__ __launch_bounds__(128, 4)
void adder_conv(const float* __restrict__ x, const float* __restrict__ wP,
                float* __restrict__ y, double* __restrict__ st,
                int Cin, int H, int W, int Wo, int stride, int pad,
                int K, int Cout, int chunks, int P, int PI)
{
    const int t    = threadIdx.x;
    const int lane = t & 63;
    const int wid  = __builtin_amdgcn_readfirstlane(t >> 6);   // 0/1, uniform
    const int otile = (blockIdx.x * 2 + wid) * OB;             // uniform
    const int p    = blockIdx.y * 64 + lane;
    const bool pvalid = p < P;

    // per-lane pixel decode (once)
    int n = 0, q = 0;
    if (pvalid) { n = p / PI; q = p - n * PI; }
    const int oh = q / Wo, ow = q - oh * Wo;
    const int ih0 = oh * stride - pad, iw0 = ow * stride - pad;
    const int HWi = H * W;
    const int xbase = n * Cin * HWi;            // < 2^31 for all layers

    float acc[OB];
#pragma unroll
    for (int i = 0; i < OB; ++i) acc[i] = 0.f;

    const float* wPo = wP + (size_t)otile * K;  // uniform base

    for (int ch = 0; ch < chunks; ++ch) {
        const int k0 = ch * 32;                 // uniform
        int c0, ih, iw;
        if (IS3x3) {
            const int tap = k0 / Cin;           // uniform (Cin % 32 == 0)
            c0 = k0 - tap * Cin;
            const int kh = tap / 3, kw = tap - kh * 3;
            ih = ih0 + kh; iw = iw0 + kw;
        } else { c0 = k0; ih = ih0; iw = iw0; }
        const bool vld = pvalid &&
            (!IS3x3 || ((unsigned)ih < (unsigned)H && (unsigned)iw < (unsigned)W));
        // clamped offset: OOB/invalid lanes read offset 0 (in-bounds), then
        // get zeroed by cndmask -> unconditional coalesced loads, no branch.
        const int off0 = vld ? (xbase + c0 * HWi + ih * W + iw) : 0;

        float xreg[32];
#pragma unroll
        for (int kk = 0; kk < 32; ++kk) {
            const float raw = x[off0 + kk * HWi];
            xreg[kk] = vld ? raw : 0.f;
        }

        // ---- och pairs: weights uniform -> s_load; 2 indep acc chains
#pragma unroll
        for (int ob = 0; ob < OB; ob += 2) {
            const float* w0 = wPo + (size_t)ob * K + k0;
            const float* w1 = w0 + K;
            float a0 = acc[ob], a1 = acc[ob + 1];
#pragma unroll
            for (int kk = 0; kk < 32; ++kk) {
                a0 += __builtin_fabsf(xreg[kk] - w0[kk]);
                a1 += __builtin_fabsf(xreg[kk] - w1[kk]);
            }
            acc[ob] = a0; acc[ob + 1] = a1;
        }
    }

    // ---- epilogue: negate, store final y, in-register BN stats
#pragma unroll
    for (int ob = 0; ob < OB; ++ob) {
        const int o = otile + ob;
        const float v = pvalid ? -acc[ob] : 0.f;
        if (pvalid) y[((size_t)n * Cout + o) * PI + q] = v;
        float s = v, s2 = v * v;
#pragma unroll
        for (int m = 32; m > 0; m >>= 1) {
            s  += __shfl_xor(s,  m);
            s2 += __shfl_xor(s2, m);
        }
        if (lane == 0) {
            unsafeAtomicAdd(&st[2 * o],     (double)s);
            unsafeAtomicAdd(&st[2 * o + 1], (double)s2);
        }
    }
}

// per-channel affine fold: a = g*rsqrt(var+eps), b = beta - mean*a
__global__ void ab_kernel(const double* __restrict__ st, const float* __restrict__ gamma,
                          const float* __restrict__ beta, float2* __restrict__ ab,
                          int C, double invCount)
{
    const int c = blockIdx.x * blockDim.x + threadIdx.x;
    if (c < C) {
        const double mean = st[2 * c] * invCount;
        const double var  = st[2 * c + 1] * invCount - mean * mean;
        const float a = gamma[c] * rsqrtf((float)var + 1e-5f);
        const float b = beta[c] - (float)mean * a;
        ab[c] = make_float2(a, b);
    }
}

// BN+ReLU6 materialize: dst[n,c,:] = clamp(a*y+b, 0, 6). blockIdx.y = n*C + c.
__global__ void prep_kernel(const float* __restrict__ y, const float2* __restrict__ ab,
                            float* __restrict__ dst, int C, int PI)
{
    const int c = blockIdx.y % C;
    const int i = blockIdx.x * 256 + threadIdx.x;
    if (i < PI) {
        const size_t base = (size_t)blockIdx.y * PI;
        const float2 s = ab[c];
        dst[base + i] = fminf(fmaxf(fmaf(s.x, y[base + i], s.y), 0.f), 6.f);
    }
}

// merged weight transposes: w [o][c][tap] -> wP [o][tap][c]  (k = tap*Cin+c)
struct TDesc { const float* w; float* wP; int Cin; int Tap; int K; int elems; };
struct TPack { TDesc d[6]; };

__global__ void transpose_all(TPack p)
{
    const TDesc d = p.d[blockIdx.y];
    const int i = blockIdx.x * 256 + threadIdx.x;
    if (i < d.elems) {
        const int o = i / d.K, r = i - o * d.K;
        const int tap = r / d.Cin, c = r - tap * d.Cin;
        d.wP[i] = d.w[((size_t)o * d.Cin + c) * d.Tap + tap];
    }
}

extern "C" void kernel_launch(void* const* d_in, const int* in_sizes, int n_in,
                              void* d_out, int out_size, void* d_ws, size_t ws_size,
                              hipStream_t stream)
{
    const float* x = (const float*)d_in[0];
    const float *w[6], *g[6], *bt[6];
    for (int i = 0; i < 6; ++i) {
        w[i]  = (const float*)d_in[1 + 3 * i];
        g[i]  = (const float*)d_in[2 + 3 * i];
        bt[i] = (const float*)d_in[3 + 3 * i];
    }

    char* ws = (char*)d_ws;
    float* bufY = (float*)ws;                                   // 23,658,496 B
    float* bufX = (float*)(ws + 23658496);                      // 23,658,496 B
    size_t off = 2ull * 23658496;
    const int wElems[6] = {256 * 512, 512 * 2304, 128 * 512,
                           256 * 1152, 128 * 256, 256 * 1152};
    float* wP[6];
    for (int i = 0; i < 6; ++i) { wP[i] = (float*)(ws + off); off += (size_t)wElems[i] * 4; }
    double* st = (double*)(ws + off); off += 3072 * 8;
    float2* ab = (float2*)(ws + off);
    const int stOff[6] = {0, 512, 1536, 1792, 2304, 2560};
    const int abOff[6] = {0, 256, 768, 896, 1152, 1280};

    const dim3 blk(256);
    const dim3 cblk(128);

    // zero stats accumulators (ws is poisoned 0xAA before every launch)
    hipMemsetAsync(st, 0, 3072 * 8, stream);

    // merged weight transposes (k = tap-major)
    TPack tp;
    const int wCin[6] = {512, 256, 512, 128, 256, 128};
    const int wTap[6] = {1, 9, 1, 9, 1, 9};
    for (int i = 0; i < 6; ++i)
        tp.d[i] = TDesc{w[i], wP[i], wCin[i], wTap[i], wCin[i] * wTap[i], wElems[i]};
    transpose_all<<<dim3((1179648 + 255) / 256, 6), blk, 0, stream>>>(tp);

    // ---- L1: 1x1, 512->256, 38x38, P=23104, PI=1444, K=512, OB=32 (1444 blk)
    adder_conv<32, false><<<dim3(4, 361), cblk, 0, stream>>>(
        x, wP[0], bufY, st + stOff[0], 512, 38, 38, 38, 1, 0, 512, 256, 16, 23104, 1444);
    ab_kernel<<<1, blk, 0, stream>>>(st + stOff[0], g[0], bt[0], ab + abOff[0], 256, 1.0 / 23104);
    prep_kernel<<<dim3(6, 16 * 256), blk, 0, stream>>>(bufY, ab + abOff[0], bufX, 256, 1444);

    // ---- L2: 3x3 s2 p1, 256->512, 38->19, P=5776, PI=361, K=2304, OB=32 (728 blk)
    adder_conv<32, true><<<dim3(8, 91), cblk, 0, stream>>>(
        bufX, wP[1], bufY, st + stOff[1], 256, 38, 38, 19, 2, 1, 2304, 512, 72, 5776, 361);
    ab_kernel<<<2, blk, 0, stream>>>(st + stOff[1], g[1], bt[1], ab + abOff[1], 512, 1.0 / 5776);
    prep_kernel<<<dim3(2, 16 * 512), blk, 0, stream>>>(bufY, ab + abOff[1], bufX, 512, 361);

    // ---- L3: 1x1, 512->128, 19x19, P=5776, PI=361, K=512, OB=16 (364 blk)
    adder_conv<16, false><<<dim3(4, 91), cblk, 0, stream>>>(
        bufX, wP[2], bufY, st + stOff[2], 512, 19, 19, 19, 1, 0, 512, 128, 16, 5776, 361);
    ab_kernel<<<1, blk, 0, stream>>>(st + stOff[2], g[2], bt[2], ab + abOff[2], 128, 1.0 / 5776);
    prep_kernel<<<dim3(2, 16 * 128), blk, 0, stream>>>(bufY, ab + abOff[2], bufX, 128, 361);

    // ---- L4: 3x3 s2 p1, 128->256, 19->10, P=1600, PI=100, K=1152, OB=16 (200 blk)
    adder_conv<16, true><<<dim3(8, 25), cblk, 0, stream>>>(
        bufX, wP[3], bufY, st + stOff[3], 128, 19, 19, 10, 2, 1, 1152, 256, 36, 1600, 100);
    ab_kernel<<<1, blk, 0, stream>>>(st + stOff[3], g[3], bt[3], ab + abOff[3], 256, 1.0 / 1600);
    prep_kernel<<<dim3(1, 16 * 256), blk, 0, stream>>>(bufY, ab + abOff[3], bufX, 256, 100);

    // ---- L5: 1x1, 256->128, 10x10, P=1600, PI=100, K=256, OB=8 (200 blk)
    adder_conv<8, false><<<dim3(8, 25), cblk, 0, stream>>>(
        bufX, wP[4], bufY, st + stOff[4], 256, 10, 10, 10, 1, 0, 256, 128, 8, 1600, 100);
    ab_kernel<<<1, blk, 0, stream>>>(st + stOff[4], g[4], bt[4], ab + abOff[4], 128, 1.0 / 1600);
    prep_kernel<<<dim3(1, 16 * 128), blk, 0, stream>>>(bufY, ab + abOff[4], bufX, 128, 100);

    // ---- L6: 3x3 s2 p0, 128->256, 10->4, P=256, PI=16, K=1152, OB=4 (128 blk)
    adder_conv<4, true><<<dim3(32, 4), cblk, 0, stream>>>(
        bufX, wP[5], bufY, st + stOff[5], 128, 10, 10, 4, 2, 0, 1152, 256, 36, 256, 16);
    ab_kernel<<<1, blk, 0, stream>>>(st + stOff[5], g[5], bt[5], ab + abOff[5], 256, 1.0 / 256);
    prep_kernel<<<dim3(1, 16 * 256), blk, 0, stream>>>(bufY, ab + abOff[5], (float*)d_out, 256, 16);
}

// Round 7
// 1576.504 us; speedup vs baseline: 1.4105x; 1.4105x over previous
//
#include <hip/hip_runtime.h>

// ---------------------------------------------------------------------------
// AdderNet 6-layer stack on MI355X (gfx950).
// out[n,o,p] = -sum_k |x[p,k] - w[o,k]|   (VALU-bound; no MFMA possible)
//
// R7: LDS-free conv sized INSIDE the compiler's register comfort zone.
// Empirical law (R2/R3/R5/R6): >~45 live floats/thread => scheduler
// re-materializes/re-loads (731MB L2 re-read traffic, VALU 33%); <=35 =>
// clean codegen. So: OCH=8 och/wave, KC=16 k/chunk -> xr[16]+acc[8] ~ 30.
// Weights are wave-uniform -> s_load -> inline SGPR operands (free pipe,
// no LDS, no barriers). x loads: 32-bit voffset, 1 v_add each, cndmask
// only for 3x3 padding. Och pairs = 2 indep acc chains (cover add latency).
// BN+ReLU6 materialized between layers by prep_kernel; stats fused into
// conv epilogue via shfl-reduce + f64 atomics.
// ---------------------------------------------------------------------------

template <int OCH, int KC, bool IS3x3>
__global__ __launch_bounds__(256)
void adder_conv(const float* __restrict__ x, const float* __restrict__ wP,
                float* __restrict__ y, double* __restrict__ st,
                int Cin, int H, int W, int Wo, int stride, int pad,
                int K, int Cout, int chunks, int P, int PI)
{
    const int lane = threadIdx.x & 63;
    const int wid  = threadIdx.x >> 6;
    // uniform och-group: block supplies 4 adjacent groups (x shared via L1)
    const int otile = __builtin_amdgcn_readfirstlane((blockIdx.x * 4 + wid) * OCH);
    const int p = blockIdx.y * 64 + lane;
    const bool pvalid = p < P;

    // per-lane pixel decode (once); invalid lanes clamp to pixel 0 (safe addr)
    int n = 0, q = 0;
    if (pvalid) { n = p / PI; q = p - n * PI; }
    const int oh = q / Wo, ow = q - oh * Wo;
    const int ih0 = oh * stride - pad, iw0 = ow * stride - pad;
    const int HWi = H * W;
    const int xbase = n * Cin * HWi;           // fits 32-bit for all layers

    float acc[OCH];
#pragma unroll
    for (int i = 0; i < OCH; ++i) acc[i] = 0.f;

    const float* wbase = wP + (size_t)otile * K;   // uniform

    for (int ch = 0; ch < chunks; ++ch) {
        const int k0 = ch * KC;                // uniform
        int c0 = k0, ih = ih0, iw = iw0;
        if (IS3x3) {
            const int tap = k0 / Cin;          // uniform (KC divides Cin)
            c0 = k0 - tap * Cin;
            const int kh = tap / 3, kw = tap - kh * 3;
            ih = ih0 + kh; iw = iw0 + kw;
        }
        bool vld = pvalid;
        if (IS3x3)
            vld = pvalid && ((unsigned)ih < (unsigned)H && (unsigned)iw < (unsigned)W);
        const int off = vld ? (xbase + c0 * HWi + ih * W + iw) : 0;

        // ---- x chunk into registers: unconditional coalesced loads.
        //      1x1: invalid-p garbage is masked at epilogue (no cndmask).
        //      3x3: padding lanes must be exactly 0 -> cndmask per load.
        float xr[KC];
#pragma unroll
        for (int kk = 0; kk < KC; ++kk) {
            const float raw = x[off + kk * HWi];
            xr[kk] = IS3x3 ? (vld ? raw : 0.f) : raw;
        }

        // ---- och pairs: uniform weight rows -> s_load -> SGPR operands
#pragma unroll
        for (int ob = 0; ob < OCH; ob += 2) {
            const float* __restrict__ w0 = wbase + ob * K + k0;
            const float* __restrict__ w1 = w0 + K;
            float a0 = acc[ob], a1 = acc[ob + 1];
#pragma unroll
            for (int kk = 0; kk < KC; ++kk) {
                a0 += __builtin_fabsf(xr[kk] - w0[kk]);
                a1 += __builtin_fabsf(xr[kk] - w1[kk]);
            }
            acc[ob] = a0; acc[ob + 1] = a1;
        }
    }

    // ---- epilogue: negate, store y, in-register BN stats (valid lanes only)
#pragma unroll
    for (int ob = 0; ob < OCH; ++ob) {
        const int o = otile + ob;
        const float v = pvalid ? -acc[ob] : 0.f;
        if (pvalid) y[((size_t)n * Cout + o) * PI + q] = v;
        float s = v, s2 = v * v;
#pragma unroll
        for (int m = 32; m > 0; m >>= 1) {
            s  += __shfl_xor(s,  m);
            s2 += __shfl_xor(s2, m);
        }
        if (lane == 0) {
            unsafeAtomicAdd(&st[2 * o],     (double)s);
            unsafeAtomicAdd(&st[2 * o + 1], (double)s2);
        }
    }
}

// per-channel affine fold: a = g*rsqrt(var+eps), b = beta - mean*a
__global__ void ab_kernel(const double* __restrict__ st, const float* __restrict__ gamma,
                          const float* __restrict__ beta, float2* __restrict__ ab,
                          int C, double invCount)
{
    const int c = blockIdx.x * blockDim.x + threadIdx.x;
    if (c < C) {
        const double mean = st[2 * c] * invCount;
        const double var  = st[2 * c + 1] * invCount - mean * mean;
        const float a = gamma[c] * rsqrtf((float)var + 1e-5f);
        const float b = beta[c] - (float)mean * a;
        ab[c] = make_float2(a, b);
    }
}

// BN+ReLU6 materialize: dst[n,c,:] = clamp(a*y+b, 0, 6). blockIdx.y = n*C + c.
__global__ void prep_kernel(const float* __restrict__ y, const float2* __restrict__ ab,
                            float* __restrict__ dst, int C, int PI)
{
    const int c = blockIdx.y % C;
    const int i = blockIdx.x * 256 + threadIdx.x;
    if (i < PI) {
        const size_t base = (size_t)blockIdx.y * PI;
        const float2 s = ab[c];
        dst[base + i] = fminf(fmaxf(fmaf(s.x, y[base + i], s.y), 0.f), 6.f);
    }
}

// merged weight transposes: w [o][c][tap] -> wP [o][tap*Cin + c]
struct TDesc { const float* w; float* wP; int Cin; int Tap; int K; int elems; };
struct TPack { TDesc d[6]; };

__global__ void transpose_all(TPack p)
{
    const TDesc d = p.d[blockIdx.y];
    const int i = blockIdx.x * 256 + threadIdx.x;
    if (i < d.elems) {
        const int o = i / d.K, r = i - o * d.K;
        const int tap = r / d.Cin, c = r - tap * d.Cin;
        d.wP[i] = d.w[((size_t)o * d.Cin + c) * d.Tap + tap];
    }
}

extern "C" void kernel_launch(void* const* d_in, const int* in_sizes, int n_in,
                              void* d_out, int out_size, void* d_ws, size_t ws_size,
                              hipStream_t stream)
{
    const float* x = (const float*)d_in[0];
    const float *w[6], *g[6], *bt[6];
    for (int i = 0; i < 6; ++i) {
        w[i]  = (const float*)d_in[1 + 3 * i];
        g[i]  = (const float*)d_in[2 + 3 * i];
        bt[i] = (const float*)d_in[3 + 3 * i];
    }

    char* ws = (char*)d_ws;
    float* bufY = (float*)ws;                                   // 23,658,496 B
    float* bufX = (float*)(ws + 23658496);                      // 23,658,496 B
    size_t off = 2ull * 23658496;
    const int wElems[6] = {256 * 512, 512 * 2304, 128 * 512,
                           256 * 1152, 128 * 256, 256 * 1152};
    float* wP[6];
    for (int i = 0; i < 6; ++i) { wP[i] = (float*)(ws + off); off += (size_t)wElems[i] * 4; }
    double* st = (double*)(ws + off); off += 3072 * 8;
    float2* ab = (float2*)(ws + off);
    const int stOff[6] = {0, 512, 1536, 1792, 2304, 2560};
    const int abOff[6] = {0, 256, 768, 896, 1152, 1280};

    const dim3 blk(256);

    // zero stats accumulators (ws is poisoned 0xAA before every launch)
    hipMemsetAsync(st, 0, 3072 * 8, stream);

    // merged weight transposes (k = tap-major)
    TPack tp;
    const int wCin[6] = {512, 256, 512, 128, 256, 128};
    const int wTap[6] = {1, 9, 1, 9, 1, 9};
    for (int i = 0; i < 6; ++i)
        tp.d[i] = TDesc{w[i], wP[i], wCin[i], wTap[i], wCin[i] * wTap[i], wElems[i]};
    transpose_all<<<dim3((1179648 + 255) / 256, 6), blk, 0, stream>>>(tp);

    // ---- L1: 1x1, 512->256, 38x38, P=23104, PI=1444, K=512 (2888 blocks)
    adder_conv<8, 16, false><<<dim3(8, 361), blk, 0, stream>>>(
        x, wP[0], bufY, st + stOff[0], 512, 38, 38, 38, 1, 0, 512, 256, 32, 23104, 1444);
    ab_kernel<<<1, blk, 0, stream>>>(st + stOff[0], g[0], bt[0], ab + abOff[0], 256, 1.0 / 23104);
    prep_kernel<<<dim3(6, 16 * 256), blk, 0, stream>>>(bufY, ab + abOff[0], bufX, 256, 1444);

    // ---- L2: 3x3 s2 p1, 256->512, 38->19, P=5776, PI=361, K=2304 (1456 blocks)
    adder_conv<8, 16, true><<<dim3(16, 91), blk, 0, stream>>>(
        bufX, wP[1], bufY, st + stOff[1], 256, 38, 38, 19, 2, 1, 2304, 512, 144, 5776, 361);
    ab_kernel<<<2, blk, 0, stream>>>(st + stOff[1], g[1], bt[1], ab + abOff[1], 512, 1.0 / 5776);
    prep_kernel<<<dim3(2, 16 * 512), blk, 0, stream>>>(bufY, ab + abOff[1], bufX, 512, 361);

    // ---- L3: 1x1, 512->128, 19x19, P=5776, PI=361, K=512 (364 blocks)
    adder_conv<8, 16, false><<<dim3(4, 91), blk, 0, stream>>>(
        bufX, wP[2], bufY, st + stOff[2], 512, 19, 19, 19, 1, 0, 512, 128, 32, 5776, 361);
    ab_kernel<<<1, blk, 0, stream>>>(st + stOff[2], g[2], bt[2], ab + abOff[2], 128, 1.0 / 5776);
    prep_kernel<<<dim3(2, 16 * 128), blk, 0, stream>>>(bufY, ab + abOff[2], bufX, 128, 361);

    // ---- L4: 3x3 s2 p1, 128->256, 19->10, P=1600, PI=100, K=1152 (200 blocks)
    adder_conv<8, 16, true><<<dim3(8, 25), blk, 0, stream>>>(
        bufX, wP[3], bufY, st + stOff[3], 128, 19, 19, 10, 2, 1, 1152, 256, 72, 1600, 100);
    ab_kernel<<<1, blk, 0, stream>>>(st + stOff[3], g[3], bt[3], ab + abOff[3], 256, 1.0 / 1600);
    prep_kernel<<<dim3(1, 16 * 256), blk, 0, stream>>>(bufY, ab + abOff[3], bufX, 256, 100);

    // ---- L5: 1x1, 256->128, 10x10, P=1600, PI=100, K=256 (100 blocks)
    adder_conv<8, 16, false><<<dim3(4, 25), blk, 0, stream>>>(
        bufX, wP[4], bufY, st + stOff[4], 256, 10, 10, 10, 1, 0, 256, 128, 16, 1600, 100);
    ab_kernel<<<1, blk, 0, stream>>>(st + stOff[4], g[4], bt[4], ab + abOff[4], 128, 1.0 / 1600);
    prep_kernel<<<dim3(1, 16 * 128), blk, 0, stream>>>(bufY, ab + abOff[4], bufX, 128, 100);

    // ---- L6: 3x3 s2 p0, 128->256, 10->4, P=256, PI=16, K=1152 (32 blocks)
    adder_conv<8, 16, true><<<dim3(8, 4), blk, 0, stream>>>(
        bufX, wP[5], bufY, st + stOff[5], 128, 10, 10, 4, 2, 0, 1152, 256, 72, 256, 16);
    ab_kernel<<<1, blk, 0, stream>>>(st + stOff[5], g[5], bt[5], ab + abOff[5], 256, 1.0 / 256);
    prep_kernel<<<dim3(1, 16 * 256), blk, 0, stream>>>(bufY, ab + abOff[5], (float*)d_out, 256, 16);
}

// Round 8
// 1421.157 us; speedup vs baseline: 1.5647x; 1.1093x over previous
//
#include <hip/hip_runtime.h>

// ---------------------------------------------------------------------------
// AdderNet 6-layer stack on MI355X (gfx950).
// out[n,o,p] = -sum_k |x[p,k] - w[o,k]|   (VALU-bound; no MFMA possible)
//
// R8: hybrid data paths.
//   - x: staged per 16-k chunk into LDS (4 KB), shared DETERMINISTICALLY by
//     all 4 waves (R7 lesson: register-only sharing via L1 drifts -> 1.95 GB
//     re-read traffic). Read once per chunk into xr[16] regs, reused by 16 och.
//   - w: wave-uniform -> scalar s_load pipe (free), no LDS for weights.
//   - och = 16/wave, 64/block -> x traffic / 8 vs R7.
//   - XCD-affinity: 1-D grid, och_group = bid % OG (OG=8 => one och-group
//     per XCD; its weight slice stays hot in that XCD's L2). Perf-only.
//   - live floats ~38/thread: inside the proven-clean register zone
//     (R1 ~30 clean @ VGPR 60; R3/R5/R6 starved at >=48 live).
// BN+ReLU6 materialized between layers by prep_kernel; per-channel stats
// fused into conv epilogue (shfl reduce + f64 atomics).
// ---------------------------------------------------------------------------

template <int OCH, bool IS3x3>
__global__ __launch_bounds__(256)
void adder_conv(const float* __restrict__ x, const float* __restrict__ wP,
                float* __restrict__ y, double* __restrict__ st,
                int Cin, int H, int W, int Wo, int stride, int pad,
                int K, int Cout, int chunks, int P, int PI, int OG)
{
    constexpr int KC = 16;
    __shared__ float xs[KC][64];               // 4 KB

    const int t    = threadIdx.x;
    const int lane = t & 63;
    const int wid  = t >> 6;                   // 0..3
    const int bid  = blockIdx.x;
    const int og   = bid % OG;                 // XCD-affine och group
    const int pb   = bid / OG;
    const int otile = __builtin_amdgcn_readfirstlane((og * 4 + wid) * OCH);

    const int p = pb * 64 + lane;
    const bool pvalid = p < P;

    // per-lane pixel decode (once); invalid lanes clamp to a safe address
    int n = 0, q = 0;
    if (pvalid) { n = p / PI; q = p - n * PI; }
    const int oh = q / Wo, ow = q - oh * Wo;
    const int ih0 = oh * stride - pad, iw0 = ow * stride - pad;
    const int HWi = H * W;
    const int xbase = n * Cin * HWi;           // fits 32-bit for all layers

    float acc[OCH];
#pragma unroll
    for (int i = 0; i < OCH; ++i) acc[i] = 0.f;

    const float* wbase = wP + (size_t)otile * K;   // uniform

    for (int ch = 0; ch < chunks; ++ch) {
        const int k0 = ch * KC;                // uniform
        int c0 = k0, ih = ih0, iw = iw0;
        if (IS3x3) {
            const int tap = k0 / Cin;          // uniform (16 divides Cin)
            c0 = k0 - tap * Cin;
            const int kh = tap / 3, kw = tap - kh * 3;
            ih = ih0 + kh; iw = iw0 + kw;
        }
        bool vld = pvalid;
        if (IS3x3)
            vld = pvalid && ((unsigned)ih < (unsigned)H && (unsigned)iw < (unsigned)W);
        const int off = vld ? (xbase + c0 * HWi + ih * W + iw) : 0;

        // ---- stage x chunk: 256 threads cover 16 rows x 64 pixels.
        //      thread (wid, lane): pixel = lane, rows wid + 4j. Coalesced
        //      across lanes; padding/OOB lanes stage literal 0.
        __syncthreads();                       // xs free (prev chunk done)
#pragma unroll
        for (int j = 0; j < 4; ++j) {
            const int row = wid + 4 * j;
            const float raw = x[off + row * HWi];
            xs[row][lane] = vld ? raw : 0.f;
        }
        __syncthreads();

        // ---- xr once per chunk (16 ds_read_b32), reused by all OCH
        float xr[KC];
#pragma unroll
        for (int kk = 0; kk < KC; ++kk) xr[kk] = xs[kk][lane];

        // ---- och pairs: uniform weight rows -> s_load -> SGPR operands
#pragma unroll
        for (int ob = 0; ob < OCH; ob += 2) {
            const float* __restrict__ w0 = wbase + ob * K + k0;
            const float* __restrict__ w1 = w0 + K;
            float a0 = acc[ob], a1 = acc[ob + 1];
#pragma unroll
            for (int kk = 0; kk < KC; ++kk) {
                a0 += __builtin_fabsf(xr[kk] - w0[kk]);
                a1 += __builtin_fabsf(xr[kk] - w1[kk]);
            }
            acc[ob] = a0; acc[ob + 1] = a1;
        }
    }

    // ---- epilogue: negate, store y, in-register BN stats
#pragma unroll
    for (int ob = 0; ob < OCH; ++ob) {
        const int o = otile + ob;
        const float v = pvalid ? -acc[ob] : 0.f;
        if (pvalid) y[((size_t)n * Cout + o) * PI + q] = v;
        float s = v, s2 = v * v;
#pragma unroll
        for (int m = 32; m > 0; m >>= 1) {
            s  += __shfl_xor(s,  m);
            s2 += __shfl_xor(s2, m);
        }
        if (lane == 0) {
            unsafeAtomicAdd(&st[2 * o],     (double)s);
            unsafeAtomicAdd(&st[2 * o + 1], (double)s2);
        }
    }
}

// per-channel affine fold: a = g*rsqrt(var+eps), b = beta - mean*a
__global__ void ab_kernel(const double* __restrict__ st, const float* __restrict__ gamma,
                          const float* __restrict__ beta, float2* __restrict__ ab,
                          int C, double invCount)
{
    const int c = blockIdx.x * blockDim.x + threadIdx.x;
    if (c < C) {
        const double mean = st[2 * c] * invCount;
        const double var  = st[2 * c + 1] * invCount - mean * mean;
        const float a = gamma[c] * rsqrtf((float)var + 1e-5f);
        const float b = beta[c] - (float)mean * a;
        ab[c] = make_float2(a, b);
    }
}

// BN+ReLU6 materialize: dst[n,c,:] = clamp(a*y+b, 0, 6). blockIdx.y = n*C + c.
__global__ void prep_kernel(const float* __restrict__ y, const float2* __restrict__ ab,
                            float* __restrict__ dst, int C, int PI)
{
    const int c = blockIdx.y % C;
    const int i = blockIdx.x * 256 + threadIdx.x;
    if (i < PI) {
        const size_t base = (size_t)blockIdx.y * PI;
        const float2 s = ab[c];
        dst[base + i] = fminf(fmaxf(fmaf(s.x, y[base + i], s.y), 0.f), 6.f);
    }
}

// merged weight transposes: w [o][c][tap] -> wP [o][tap*Cin + c]
struct TDesc { const float* w; float* wP; int Cin; int Tap; int K; int elems; };
struct TPack { TDesc d[6]; };

__global__ void transpose_all(TPack p)
{
    const TDesc d = p.d[blockIdx.y];
    const int i = blockIdx.x * 256 + threadIdx.x;
    if (i < d.elems) {
        const int o = i / d.K, r = i - o * d.K;
        const int tap = r / d.Cin, c = r - tap * d.Cin;
        d.wP[i] = d.w[((size_t)o * d.Cin + c) * d.Tap + tap];
    }
}

extern "C" void kernel_launch(void* const* d_in, const int* in_sizes, int n_in,
                              void* d_out, int out_size, void* d_ws, size_t ws_size,
                              hipStream_t stream)
{
    const float* x = (const float*)d_in[0];
    const float *w[6], *g[6], *bt[6];
    for (int i = 0; i < 6; ++i) {
        w[i]  = (const float*)d_in[1 + 3 * i];
        g[i]  = (const float*)d_in[2 + 3 * i];
        bt[i] = (const float*)d_in[3 + 3 * i];
    }

    char* ws = (char*)d_ws;
    float* bufY = (float*)ws;                                   // 23,658,496 B
    float* bufX = (float*)(ws + 23658496);                      // 23,658,496 B
    size_t off = 2ull * 23658496;
    const int wElems[6] = {256 * 512, 512 * 2304, 128 * 512,
                           256 * 1152, 128 * 256, 256 * 1152};
    float* wP[6];
    for (int i = 0; i < 6; ++i) { wP[i] = (float*)(ws + off); off += (size_t)wElems[i] * 4; }
    double* st = (double*)(ws + off); off += 3072 * 8;
    float2* ab = (float2*)(ws + off);
    const int stOff[6] = {0, 512, 1536, 1792, 2304, 2560};
    const int abOff[6] = {0, 256, 768, 896, 1152, 1280};

    const dim3 blk(256);

    // zero stats accumulators (ws is poisoned 0xAA before every launch)
    hipMemsetAsync(st, 0, 3072 * 8, stream);

    // merged weight transposes (k = tap-major)
    TPack tp;
    const int wCin[6] = {512, 256, 512, 128, 256, 128};
    const int wTap[6] = {1, 9, 1, 9, 1, 9};
    for (int i = 0; i < 6; ++i)
        tp.d[i] = TDesc{w[i], wP[i], wCin[i], wTap[i], wCin[i] * wTap[i], wElems[i]};
    transpose_all<<<dim3((1179648 + 255) / 256, 6), blk, 0, stream>>>(tp);

    // ---- L1: 1x1, 512->256, 38x38, P=23104, K=512. OCH=16, OG=4 (1444 blk)
    adder_conv<16, false><<<dim3(4 * 361), blk, 0, stream>>>(
        x, wP[0], bufY, st + stOff[0], 512, 38, 38, 38, 1, 0, 512, 256, 32, 23104, 1444, 4);
    ab_kernel<<<1, blk, 0, stream>>>(st + stOff[0], g[0], bt[0], ab + abOff[0], 256, 1.0 / 23104);
    prep_kernel<<<dim3(6, 16 * 256), blk, 0, stream>>>(bufY, ab + abOff[0], bufX, 256, 1444);

    // ---- L2: 3x3 s2 p1, 256->512, 38->19, P=5776, K=2304. OCH=16, OG=8 (728 blk)
    adder_conv<16, true><<<dim3(8 * 91), blk, 0, stream>>>(
        bufX, wP[1], bufY, st + stOff[1], 256, 38, 38, 19, 2, 1, 2304, 512, 144, 5776, 361, 8);
    ab_kernel<<<2, blk, 0, stream>>>(st + stOff[1], g[1], bt[1], ab + abOff[1], 512, 1.0 / 5776);
    prep_kernel<<<dim3(2, 16 * 512), blk, 0, stream>>>(bufY, ab + abOff[1], bufX, 512, 361);

    // ---- L3: 1x1, 512->128, 19x19, P=5776, K=512. OCH=8, OG=4 (364 blk)
    adder_conv<8, false><<<dim3(4 * 91), blk, 0, stream>>>(
        bufX, wP[2], bufY, st + stOff[2], 512, 19, 19, 19, 1, 0, 512, 128, 32, 5776, 361, 4);
    ab_kernel<<<1, blk, 0, stream>>>(st + stOff[2], g[2], bt[2], ab + abOff[2], 128, 1.0 / 5776);
    prep_kernel<<<dim3(2, 16 * 128), blk, 0, stream>>>(bufY, ab + abOff[2], bufX, 128, 361);

    // ---- L4: 3x3 s2 p1, 128->256, 19->10, P=1600, K=1152. OCH=8, OG=8 (200 blk)
    adder_conv<8, true><<<dim3(8 * 25), blk, 0, stream>>>(
        bufX, wP[3], bufY, st + stOff[3], 128, 19, 19, 10, 2, 1, 1152, 256, 72, 1600, 100, 8);
    ab_kernel<<<1, blk, 0, stream>>>(st + stOff[3], g[3], bt[3], ab + abOff[3], 256, 1.0 / 1600);
    prep_kernel<<<dim3(1, 16 * 256), blk, 0, stream>>>(bufY, ab + abOff[3], bufX, 256, 100);

    // ---- L5: 1x1, 256->128, 10x10, P=1600, K=256. OCH=4, OG=8 (200 blk)
    adder_conv<4, false><<<dim3(8 * 25), blk, 0, stream>>>(
        bufX, wP[4], bufY, st + stOff[4], 256, 10, 10, 10, 1, 0, 256, 128, 16, 1600, 100, 8);
    ab_kernel<<<1, blk, 0, stream>>>(st + stOff[4], g[4], bt[4], ab + abOff[4], 128, 1.0 / 1600);
    prep_kernel<<<dim3(1, 16 * 128), blk, 0, stream>>>(bufY, ab + abOff[4], bufX, 128, 100);

    // ---- L6: 3x3 s2 p0, 128->256, 10->4, P=256, K=1152. OCH=2, OG=32 (128 blk)
    adder_conv<2, true><<<dim3(32 * 4), blk, 0, stream>>>(
        bufX, wP[5], bufY, st + stOff[5], 128, 10, 10, 4, 2, 0, 1152, 256, 72, 256, 16, 32);
    ab_kernel<<<1, blk, 0, stream>>>(st + stOff[5], g[5], bt[5], ab + abOff[5], 256, 1.0 / 256);
    prep_kernel<<<dim3(1, 16 * 256), blk, 0, stream>>>(bufY, ab + abOff[5], (float*)d_out, 256, 16);
}